// Round 14
// baseline (184.943 us; speedup 1.0000x reference)
//
#include <hip/hip_runtime.h>
#include <hip/hip_fp16.h>

typedef _Float16 f16;
typedef _Float16 f16x8 __attribute__((ext_vector_type(8)));
typedef _Float16 f16x4 __attribute__((ext_vector_type(4)));
typedef float    f32x4 __attribute__((ext_vector_type(4)));
typedef float    f32x16 __attribute__((ext_vector_type(16)));

#define DEV __device__ __forceinline__

DEV int imin(int a, int b) { return a < b ? a : b; }

#if defined(__has_builtin)
#  if __has_builtin(__builtin_amdgcn_exp2f)
#    define EXP2(x) __builtin_amdgcn_exp2f(x)
#  else
#    define EXP2(x) __expf((x) * 0.6931471805599453f)
#  endif
#else
#  define EXP2(x) __expf((x) * 0.6931471805599453f)
#endif

// q pre-scale: (1/sqrt(32)) * log2(e) so softmax is p = 2^s
#define QSCALE (0.17677669529663687f * 1.4426950408889634f)

// ---------------------------------------------------------------------------
// Problem constants: B=16, N=1044, DIM=512, H=8, KD=32, D=64
// q padded to 1152 rows, k/v to 1088, o cols to 1056
// ---------------------------------------------------------------------------

// workspace offsets (bytes) — round-3/6 proven layout (XH slot unused)
constexpr size_t OFF_WQ   = 17104896;     // qkv_w fp16 (1024,512)        1,048,576
constexpr size_t OFF_PW   = 18153472;     // proj_w fp16 (1024,1056)      2,162,688
constexpr size_t OFF_OW   = 20316160;     // out_w fp16 (512,512)           524,288
constexpr size_t OFF_BNA  = 20840448;     // bn scale fp32 (1024)
constexpr size_t OFF_BNB  = 20844544;     // bn shift fp32 (1024)
constexpr size_t OFF_QB   = 20848640;     // q fp16 (128,1152,32)         9,437,184
constexpr size_t OFF_KB   = 30285824;     // k fp16 (128,1088,32)         8,912,896
constexpr size_t OFF_VT   = 39198720;     // v^T fp16 (128,64,1088)      17,825,792
constexpr size_t OFF_OPAD = 57024512;     // o fp16 (16,512,1056)        17,301,504
constexpr size_t OFF_VCT  = 74326016;     // vcT fp16 (16,1024,512)      16,777,216
constexpr size_t OFF_XOT  = 91103232;     // xoT fp16 (16,1024,512)      16,777,216

DEV f32x16 zero16() {
  f32x16 z;
  #pragma unroll
  for (int i = 0; i < 16; ++i) z[i] = 0.f;
  return z;
}

DEV unsigned pk2(float a, float b) {
  auto h = __builtin_amdgcn_cvt_pkrtz(a, b);
  union { decltype(h) x; unsigned u; } t;
  t.x = h;
  return t.u;
}

DEV void plswap(unsigned &a, unsigned &b) {
  asm("v_permlane32_swap_b32 %0, %1" : "+v"(a), "+v"(b));
}

union W4 { unsigned w[4]; f16x8 v; };

DEV void pack_block(const float p[16], f16x8 &a0, f16x8 &a1) {
  unsigned w0 = pk2(p[0], p[1]),   w1 = pk2(p[2], p[3]);
  unsigned w2 = pk2(p[4], p[5]),   w3 = pk2(p[6], p[7]);
  unsigned w4 = pk2(p[8], p[9]),   w5 = pk2(p[10], p[11]);
  unsigned w6 = pk2(p[12], p[13]), w7 = pk2(p[14], p[15]);
  plswap(w0, w2); plswap(w1, w3);
  plswap(w4, w6); plswap(w5, w7);
  W4 u; u.w[0] = w0; u.w[1] = w1; u.w[2] = w2; u.w[3] = w3; a0 = u.v;
  W4 v; v.w[0] = w4; v.w[1] = w5; v.w[2] = w6; v.w[3] = w7; a1 = v.v;
}

// ---------------------------------------------------------------------------
// prep: weight fp16 conversions, BN fold, zero pads (r13 verbatim)
// ---------------------------------------------------------------------------
__global__ __launch_bounds__(256) void prep_kernel(
    const float* __restrict__ qkv_w,
    const float* __restrict__ bn_g, const float* __restrict__ bn_b,
    const float* __restrict__ bn_m, const float* __restrict__ bn_v,
    const float* __restrict__ proj_w, const float* __restrict__ out_w,
    f16* __restrict__ wq_h, f16* __restrict__ pw_h, f16* __restrict__ ow_h,
    float* __restrict__ bn_a, float* __restrict__ bn_sh,
    f16* __restrict__ qb, f16* __restrict__ kb, f16* __restrict__ vt,
    f16* __restrict__ opad)
{
  long tid = (long)blockIdx.x * blockDim.x + threadIdx.x;
  long gsz = (long)gridDim.x * blockDim.x;

  for (long i = tid; i < 524288; i += gsz) wq_h[i] = (f16)qkv_w[i];
  for (long i = tid; i < 1081344; i += gsz) {
    long m = i / 1056, nn = i - m * 1056;
    pw_h[i] = (nn < 1044) ? (f16)proj_w[m * 1044 + nn] : (f16)0.f;
  }
  for (long i = tid; i < 262144; i += gsz) ow_h[i] = (f16)out_w[i];
  for (long i = tid; i < 1024; i += gsz) {
    float a = bn_g[i] * rsqrtf(bn_v[i] + 1e-5f);
    bn_a[i] = a;
    bn_sh[i] = bn_b[i] - bn_m[i] * a;
  }
  for (long i = tid; i < 13824; i += gsz) {
    int bh = (int)(i / 108);
    int nn = 1044 + (int)(i - (long)bh * 108);
    f16* q = qb + ((long)bh * 1152 + nn) * 32;
    for (int j = 0; j < 32; ++j) q[j] = (f16)0.f;
  }
  for (long i = tid; i < 5632; i += gsz) {
    int bh = (int)(i / 44);
    int nn = 1044 + (int)(i - (long)bh * 44);
    f16* k = kb + ((long)bh * 1088 + nn) * 32;
    for (int j = 0; j < 32; ++j) k[j] = (f16)0.f;
  }
  for (long i = tid; i < 8192; i += gsz) {
    f16* v = vt + i * 1088 + 1044;
    for (int j = 0; j < 44; ++j) v[j] = (f16)0.f;
  }
  for (long i = tid; i < 8192; i += gsz) {
    f16* o = opad + i * 1056 + 1044;
    for (int j = 0; j < 12; ++j) o[j] = (f16)0.f;
  }
}

// ---------------------------------------------------------------------------
// frag-read + 16 MFMA from one slice (proven addressing, stride 40)
// ---------------------------------------------------------------------------
DEV void mfma_slice(const f16* __restrict__ as, const f16* __restrict__ bs,
                    int wr, int wc, int fr, int fg, f32x4 acc[4][4])
{
  f16x8 af[4], bf[4];
  #pragma unroll
  for (int m = 0; m < 4; ++m)
    af[m] = *(const f16x8*)(as + (wr * 64 + m * 16 + fr) * 40 + fg * 8);
  #pragma unroll
  for (int n = 0; n < 4; ++n)
    bf[n] = *(const f16x8*)(bs + (wc * 64 + n * 16 + fr) * 40 + fg * 8);
  #pragma unroll
  for (int m = 0; m < 4; ++m)
    #pragma unroll
    for (int n = 0; n < 4; ++n)
      acc[m][n] = __builtin_amdgcn_mfma_f32_16x16x32_f16(af[m], bf[n], acc[m][n], 0, 0, 0);
}

// ---------------------------------------------------------------------------
// double-slice NT-GEMM core (f16 A, f16 B): two independent copies of the
// proven stride-40 buffers staged per barrier pair -> half the barriers,
// 2x MFMA per phase.  Address formulas byte-identical to r13's core.
// ---------------------------------------------------------------------------
DEV void gemm_core(const f16* __restrict__ A, const f16* __restrict__ B,
                   int lda, int ldb, int kIters, int rowClampA, int rowClampB,
                   f16* As0, f16* Bs0, f16* As1, f16* Bs1, f32x4 acc[4][4])
{
  const int t = threadIdx.x;
  const int wave = t >> 6, lane = t & 63;
  const int wr = wave >> 1, wc = wave & 1;
  const int r0 = t >> 2, seg = t & 3;
  const int fr = lane & 15, fg = lane >> 4;
  const int ra0 = imin(r0, rowClampA);
  const int ra1 = imin(r0 + 64, rowClampA);
  const int rb0 = imin(r0, rowClampB);
  const int rb1 = imin(r0 + 64, rowClampB);

  const f16* pa0 = A + (long)ra0 * lda + seg * 8;
  const f16* pa1 = A + (long)ra1 * lda + seg * 8;
  const f16* pb0 = B + (long)rb0 * ldb + seg * 8;
  const f16* pb1 = B + (long)rb1 * ldb + seg * 8;

  f16x8 a0_0, a1_0, b0_0, b1_0;   // slice 0 regs
  f16x8 a0_1, a1_1, b0_1, b1_1;   // slice 1 regs

  // prologue
  a0_0 = *(const f16x8*)(pa0);
  a1_0 = *(const f16x8*)(pa1);
  b0_0 = *(const f16x8*)(pb0);
  b1_0 = *(const f16x8*)(pb1);
  if (kIters > 1) {
    a0_1 = *(const f16x8*)(pa0 + 32);
    a1_1 = *(const f16x8*)(pa1 + 32);
    b0_1 = *(const f16x8*)(pb0 + 32);
    b1_1 = *(const f16x8*)(pb1 + 32);
  }

  #pragma unroll 1
  for (int k0 = 0; k0 < kIters; k0 += 2) {
    const bool has1 = (k0 + 1 < kIters);
    __syncthreads();
    *(f16x8*)(As0 + r0 * 40 + seg * 8) = a0_0;
    *(f16x8*)(As0 + (r0 + 64) * 40 + seg * 8) = a1_0;
    *(f16x8*)(Bs0 + r0 * 40 + seg * 8) = b0_0;
    *(f16x8*)(Bs0 + (r0 + 64) * 40 + seg * 8) = b1_0;
    if (has1) {
      *(f16x8*)(As1 + r0 * 40 + seg * 8) = a0_1;
      *(f16x8*)(As1 + (r0 + 64) * 40 + seg * 8) = a1_1;
      *(f16x8*)(Bs1 + r0 * 40 + seg * 8) = b0_1;
      *(f16x8*)(Bs1 + (r0 + 64) * 40 + seg * 8) = b1_1;
    }
    __syncthreads();
    if (k0 + 2 < kIters) {
      const int kb = (k0 + 2) * 32;
      a0_0 = *(const f16x8*)(pa0 + kb);
      a1_0 = *(const f16x8*)(pa1 + kb);
      b0_0 = *(const f16x8*)(pb0 + kb);
      b1_0 = *(const f16x8*)(pb1 + kb);
    }
    if (k0 + 3 < kIters) {
      const int kb = (k0 + 3) * 32;
      a0_1 = *(const f16x8*)(pa0 + kb);
      a1_1 = *(const f16x8*)(pa1 + kb);
      b0_1 = *(const f16x8*)(pb0 + kb);
      b1_1 = *(const f16x8*)(pb1 + kb);
    }
    mfma_slice(As0, Bs0, wr, wc, fr, fg, acc);
    if (has1) mfma_slice(As1, Bs1, wr, wc, fr, fg, acc);
  }
}

// ---------------------------------------------------------------------------
// double-slice variant: B side FP32 (x direct from HBM), converted in-reg
// ---------------------------------------------------------------------------
DEV void gemm_core_xf32(const f16* __restrict__ A, const float* __restrict__ B,
                        int lda, int ldb, int kIters, int rowClampB,
                        f16* As0, f16* Bs0, f16* As1, f16* Bs1,
                        f32x4 acc[4][4])
{
  const int t = threadIdx.x;
  const int wave = t >> 6, lane = t & 63;
  const int wr = wave >> 1, wc = wave & 1;
  const int r0 = t >> 2, seg = t & 3;
  const int fr = lane & 15, fg = lane >> 4;
  const int rb0 = imin(r0, rowClampB);
  const int rb1 = imin(r0 + 64, rowClampB);

  const f16*   pa0 = A + (long)r0 * lda + seg * 8;
  const f16*   pa1 = A + (long)(r0 + 64) * lda + seg * 8;
  const float* pb0 = B + (long)rb0 * ldb + seg * 8;
  const float* pb1 = B + (long)rb1 * ldb + seg * 8;

  auto cvt8 = [](float4 lo, float4 hi) -> f16x8 {
    f16x8 r;
    r[0] = (f16)lo.x; r[1] = (f16)lo.y; r[2] = (f16)lo.z; r[3] = (f16)lo.w;
    r[4] = (f16)hi.x; r[5] = (f16)hi.y; r[6] = (f16)hi.z; r[7] = (f16)hi.w;
    return r;
  };

  f16x8 a0_0, a1_0, a0_1, a1_1;
  float4 b0l_0, b0h_0, b1l_0, b1h_0;
  float4 b0l_1, b0h_1, b1l_1, b1h_1;

  a0_0 = *(const f16x8*)(pa0);
  a1_0 = *(const f16x8*)(pa1);
  b0l_0 = ((const float4*)pb0)[0]; b0h_0 = ((const float4*)pb0)[1];
  b1l_0 = ((const float4*)pb1)[0]; b1h_0 = ((const float4*)pb1)[1];
  if (kIters > 1) {
    a0_1 = *(const f16x8*)(pa0 + 32);
    a1_1 = *(const f16x8*)(pa1 + 32);
    b0l_1 = ((const float4*)(pb0 + 32))[0]; b0h_1 = ((const float4*)(pb0 + 32))[1];
    b1l_1 = ((const float4*)(pb1 + 32))[0]; b1h_1 = ((const float4*)(pb1 + 32))[1];
  }

  #pragma unroll 1
  for (int k0 = 0; k0 < kIters; k0 += 2) {
    const bool has1 = (k0 + 1 < kIters);
    __syncthreads();
    *(f16x8*)(As0 + r0 * 40 + seg * 8) = a0_0;
    *(f16x8*)(As0 + (r0 + 64) * 40 + seg * 8) = a1_0;
    *(f16x8*)(Bs0 + r0 * 40 + seg * 8) = cvt8(b0l_0, b0h_0);
    *(f16x8*)(Bs0 + (r0 + 64) * 40 + seg * 8) = cvt8(b1l_0, b1h_0);
    if (has1) {
      *(f16x8*)(As1 + r0 * 40 + seg * 8) = a0_1;
      *(f16x8*)(As1 + (r0 + 64) * 40 + seg * 8) = a1_1;
      *(f16x8*)(Bs1 + r0 * 40 + seg * 8) = cvt8(b0l_1, b0h_1);
      *(f16x8*)(Bs1 + (r0 + 64) * 40 + seg * 8) = cvt8(b1l_1, b1h_1);
    }
    __syncthreads();
    if (k0 + 2 < kIters) {
      const int kb = (k0 + 2) * 32;
      a0_0 = *(const f16x8*)(pa0 + kb);
      a1_0 = *(const f16x8*)(pa1 + kb);
      b0l_0 = ((const float4*)(pb0 + kb))[0]; b0h_0 = ((const float4*)(pb0 + kb))[1];
      b1l_0 = ((const float4*)(pb1 + kb))[0]; b1h_0 = ((const float4*)(pb1 + kb))[1];
    }
    if (k0 + 3 < kIters) {
      const int kb = (k0 + 3) * 32;
      a0_1 = *(const f16x8*)(pa0 + kb);
      a1_1 = *(const f16x8*)(pa1 + kb);
      b0l_1 = ((const float4*)(pb0 + kb))[0]; b0h_1 = ((const float4*)(pb0 + kb))[1];
      b1l_1 = ((const float4*)(pb1 + kb))[0]; b1h_1 = ((const float4*)(pb1 + kb))[1];
    }
    mfma_slice(As0, Bs0, wr, wc, fr, fg, acc);
    if (has1) mfma_slice(As1, Bs1, wr, wc, fr, fg, acc);
  }
}

// ---------------------------------------------------------------------------
// QKV GEMM, transposed: A = wq_h (f16), B = x (FP32 direct).  grid (8,131)
// ---------------------------------------------------------------------------
__global__ __launch_bounds__(256) void qkv_gemm(
    const float* __restrict__ x, const f16* __restrict__ wq,
    const float* __restrict__ bn_a, const float* __restrict__ bn_sh,
    f16* __restrict__ qb, f16* __restrict__ kb, f16* __restrict__ vt)
{
  __shared__ f16 As0[128 * 40];
  __shared__ f16 Bs0[128 * 40];
  __shared__ f16 As1[128 * 40];
  __shared__ f16 Bs1[128 * 40];
  const int id = blockIdx.x + blockIdx.y * 8;          // [0,1048)
  const int lin = (id & 7) * 131 + (id >> 3);          // bijective [0,1048)
  const int row0 = (lin & 7) * 128;                    // channel block
  const int col0 = (lin >> 3) * 128;                   // token block (banded)
  f32x4 acc[4][4];
  #pragma unroll
  for (int m = 0; m < 4; ++m)
    #pragma unroll
    for (int n = 0; n < 4; ++n) acc[m][n] = (f32x4){0.f, 0.f, 0.f, 0.f};
  gemm_core_xf32(wq + (long)row0 * 512, x + (long)col0 * 512, 512, 512, 16,
                 16703 - col0, As0, Bs0, As1, Bs1, acc);
  const int lane = threadIdx.x & 63, wave = threadIdx.x >> 6;
  const int wr = wave >> 1, wc = wave & 1, fr = lane & 15, fg = lane >> 4;
  #pragma unroll
  for (int m = 0; m < 4; ++m) {
    const int chBase = row0 + wr * 64 + m * 16 + fg * 4;   // channel quad
    const float4 ba4 = *(const float4*)(bn_a + chBase);
    const float4 bs4 = *(const float4*)(bn_sh + chBase);
    const int hh = chBase >> 7, r = chBase & 127;          // quad-uniform cat
    #pragma unroll
    for (int n = 0; n < 4; ++n) {
      int tok = col0 + wc * 64 + n * 16 + fr;
      if (tok < 16704) {
        int bi = tok / 1044;
        int ni = tok - bi * 1044;
        long bh = (long)(bi * 8 + hh);
        float v0 = acc[m][n][0] * ba4.x + bs4.x;
        float v1 = acc[m][n][1] * ba4.y + bs4.y;
        float v2 = acc[m][n][2] * ba4.z + bs4.z;
        float v3 = acc[m][n][3] * ba4.w + bs4.w;
        if (r < 32) {
          f16x4 pk = {(f16)(v0 * QSCALE), (f16)(v1 * QSCALE),
                      (f16)(v2 * QSCALE), (f16)(v3 * QSCALE)};
          *(f16x4*)(qb + (bh * 1152 + ni) * 32 + r) = pk;
        } else if (r < 64) {
          f16x4 pk = {(f16)v0, (f16)v1, (f16)v2, (f16)v3};
          *(f16x4*)(kb + (bh * 1088 + ni) * 32 + (r - 32)) = pk;
        } else {
          f16* vp = vt + (bh * 64 + (r - 64)) * 1088 + ni;
          vp[0]        = (f16)v0;
          vp[1088]     = (f16)v1;
          vp[2 * 1088] = (f16)v2;
          vp[3 * 1088] = (f16)v3;
        }
      }
    }
  }
}

// ---------------------------------------------------------------------------
// depthwise conv branch (verbatim)
// ---------------------------------------------------------------------------
__global__ __launch_bounds__(256) void conv_kernel(
    const f16* __restrict__ vt, const float* __restrict__ conv_w,
    const float* __restrict__ conv_b, f16* __restrict__ vcT)
{
  __shared__ f16 img[16][34][36];
  const int b = blockIdx.y, g = blockIdx.x;
  const int c0 = g * 16, h = c0 >> 6, ci0 = c0 & 63;
  const int t = threadIdx.x;
  for (int i = t; i < 16 * 34 * 36; i += 256) ((f16*)img)[i] = (f16)0.f;
  __syncthreads();
  const int d = t >> 2, seg = t & 3;
  const f16* src = vt + ((long)(b * 8 + h) * 64 + d) * 1088 + ci0 * 16 + seg * 64;
  const int dhib = d >> 5;
  const int s2 = d & 31;
  #pragma unroll
  for (int j = 0; j < 8; ++j) {
    f16x8 vv = *(const f16x8*)(src + j * 8);
    #pragma unroll
    for (int e = 0; e < 8; ++e) {
      int local = seg * 64 + j * 8 + e;
      int cl = local >> 4, rr = local & 15;
      float xv = (float)vv[e];
      float hs = xv * fminf(fmaxf(xv + 3.f, 0.f), 6.f) * (1.f / 6.f);
      img[cl][1 + rr * 2 + dhib][1 + s2] = (f16)hs;
    }
  }
  __syncthreads();
  const int cl = t & 15, pg = t >> 4;
  const int c = c0 + cl;
  float w[9];
  #pragma unroll
  for (int i = 0; i < 9; ++i) w[i] = conv_w[c * 9 + i];
  const float bias = conv_b[c];
  for (int i = 0; i < 64; ++i) {
    int p = pg + i * 16;
    int s1 = p >> 5, ss2 = p & 31;
    float a = bias;
    #pragma unroll
    for (int di = 0; di < 3; ++di)
      #pragma unroll
      for (int dj = 0; dj < 3; ++dj)
        a += w[di * 3 + dj] * (float)img[cl][s1 + di][ss2 + dj];
    vcT[((long)b * 1024 + p) * 512 + c] = (f16)a;
  }
}

// ---------------------------------------------------------------------------
// fused attention — r9-proven (66-68 us) verbatim.
// ---------------------------------------------------------------------------
__global__ __launch_bounds__(256, 4) void attn_kernel(
    const f16* __restrict__ qb, const f16* __restrict__ kb,
    const f16* __restrict__ vt, f16* __restrict__ opad)
{
  __shared__ f16 kls[2][4 * 32 * 8];   // 2 KB/buf
  __shared__ f16 vls[2][4 * 64 * 8];   // 4 KB/buf
  __shared__ float l_sh[4][32];

  const int id = blockIdx.x + blockIdx.y * 9;
  const int xcd = id & 7, sl = id >> 3;
  const int bh = xcd * 16 + sl / 9, qblk = sl % 9;
  const int b = bh >> 3, h = bh & 7;
  const int t = threadIdx.x;
  const int wave = t >> 6, lane = t & 63;
  const int lq = lane & 31, hi = lane >> 5;
  const int q0 = qblk * 128 + wave * 32;

  const f16* qb_ = qb + (long)bh * 1152 * 32;
  const f16* kb_ = kb + (long)bh * 1088 * 32;
  const f16* vt_ = vt + (long)bh * 64 * 1088;

  const f16x8 qf0 = *(const f16x8*)(qb_ + (long)(q0 + lq) * 32 + hi * 8);
  const f16x8 qf1 = *(const f16x8*)(qb_ + (long)(q0 + lq) * 32 + 16 + hi * 8);

  const int sk_k = t >> 3, sk_s8 = t & 7;
  const int sk_seg = sk_s8 >> 1, sk_half = sk_s8 & 1;
  const int sv_d = t >> 2, sv_p = t & 3;
  const int wkoff = (sk_seg * 32 + ((sk_k + sk_seg) & 31)) * 16 + sk_half * 8;
  const int wvoff = (sv_p * 64 + ((sv_d + sv_p) & 63)) * 16;
  int koff[2], voff[2][2];
  #pragma unroll
  for (int ss = 0; ss < 2; ++ss) {
    int ss2 = 2 * ss + hi;
    koff[ss] = (ss2 * 32 + ((lq + ss2) & 31)) * 16;
  }
  #pragma unroll
  for (int nd = 0; nd < 2; ++nd)
    #pragma unroll
    for (int ks = 0; ks < 2; ++ks) {
      int kk4 = 2 * ks + hi;
      voff[nd][ks] = (kk4 * 64 + ((nd * 32 + lq + kk4) & 63)) * 16;
    }

  f16x4 stk;
  f16x8 stv;
  auto load_tile = [&](int kt) {
    stk = *(const f16x4*)(kb_ + (long)(kt * 32 + sk_k) * 32 + sk_s8 * 4);
    stv = *(const f16x8*)(vt_ + (long)sv_d * 1088 + kt * 32 + sv_p * 8);
  };
  auto write_tile = [&](int buf) {
    *(f16x4*)((char*)kls[buf] + wkoff) = stk;
    *(f16x8*)((char*)vls[buf] + wvoff) = stv;
  };

  f32x16 o0 = zero16(), o1 = zero16();
  float lsum = 0.f;

  load_tile(0);
  write_tile(0);
  __syncthreads();

  int cur = 0;
  #pragma unroll 1
  for (int kt = 0; kt < 33; ++kt) {
    if (kt < 32) load_tile(kt + 1);
    const char* kcur = (const char*)kls[cur];
    const char* vcur = (const char*)vls[cur];
    f16x8 kf0 = *(const f16x8*)(kcur + koff[0]);
    f16x8 kf1 = *(const f16x8*)(kcur + koff[1]);
    f32x16 s = zero16();
    s = __builtin_amdgcn_mfma_f32_32x32x16_f16(kf0, qf0, s, 0, 0, 0);
    s = __builtin_amdgcn_mfma_f32_32x32x16_f16(kf1, qf1, s, 0, 0, 0);
    float p[16];
    #pragma unroll
    for (int r = 0; r < 16; ++r) p[r] = EXP2(s[r]);
    if (kt == 32) {
      #pragma unroll
      for (int r = 0; r < 16; ++r) {
        int cr = (r & 3) + 8 * (r >> 2) + 4 * hi;
        p[r] = (cr < 20) ? p[r] : 0.f;
      }
    }
    float t8[8];
    #pragma unroll
    for (int r = 0; r < 8; ++r) t8[r] = p[r] + p[r + 8];
    lsum += ((t8[0] + t8[1]) + (t8[2] + t8[3])) + ((t8[4] + t8[5]) + (t8[6] + t8[7]));
    f16x8 pa0, pa1;
    pack_block(p, pa0, pa1);
    __builtin_amdgcn_s_setprio(1);
    {
      f16x8 vf00 = *(const f16x8*)(vcur + voff[0][0]);
      f16x8 vf10 = *(const f16x8*)(vcur + voff[1][0]);
      o0 = __builtin_amdgcn_mfma_f32_32x32x16_f16(pa0, vf00, o0, 0, 0, 0);
      o1 = __builtin_amdgcn_mfma_f32_32x32x16_f16(pa0, vf10, o1, 0, 0, 0);
      f16x8 vf01 = *(const f16x8*)(vcur + voff[0][1]);
      f16x8 vf11 = *(const f16x8*)(vcur + voff[1][1]);
      o0 = __builtin_amdgcn_mfma_f32_32x32x16_f16(pa1, vf01, o0, 0, 0, 0);
      o1 = __builtin_amdgcn_mfma_f32_32x32x16_f16(pa1, vf11, o1, 0, 0, 0);
    }
    __builtin_amdgcn_s_setprio(0);
    if (kt < 32) write_tile(cur ^ 1);
    __syncthreads();
    cur ^= 1;
  }

  lsum += __shfl_xor(lsum, 32);
  l_sh[wave][lq] = lsum;
  __syncthreads();
  float invl[16];
  #pragma unroll
  for (int r = 0; r < 16; ++r) {
    int cr = (r & 3) + 8 * (r >> 2) + 4 * hi;
    invl[r] = __builtin_amdgcn_rcpf(l_sh[wave][cr]);
  }
  #pragma unroll
  for (int nd = 0; nd < 2; ++nd) {
    #pragma unroll
    for (int r = 0; r < 16; ++r) {
      int cr = (r & 3) + 8 * (r >> 2) + 4 * hi;
      int q = q0 + cr;
      if (q < 1044) {
        float val = (nd ? o1[r] : o0[r]) * invl[r];
        unsigned flat = (unsigned)q * 512u + (unsigned)h * 64u + (unsigned)(nd * 32 + lq);
        unsigned c = flat / 1044u;
        unsigned np = flat - c * 1044u;
        opad[((long)b * 512 + c) * 1056 + np] = (f16)val;
      }
    }
  }
}

// ---------------------------------------------------------------------------
// proj GEMM (double-slice core).  grid dim3(4,8,16); K=1056 -> 33 slices
// ---------------------------------------------------------------------------
__global__ __launch_bounds__(256) void proj_gemm(
    const f16* __restrict__ pw, const f16* __restrict__ opad,
    const float* __restrict__ proj_b, const f16* __restrict__ vcT,
    f16* __restrict__ xoT)
{
  __shared__ f16 As0[128 * 40];
  __shared__ f16 Bs0[128 * 40];
  __shared__ f16 As1[128 * 40];
  __shared__ f16 Bs1[128 * 40];
  const int id = blockIdx.x + blockIdx.y * 4 + blockIdx.z * 32;  // [0,512)
  const int lin = (id & 7) * 64 + (id >> 3);                     // bijective
  const int b = lin >> 5;
  const int rc = lin & 31;
  const int row0 = (rc >> 2) * 128;  // m (image pixel)
  const int col0 = (rc & 3) * 128;   // c (channel)
  f32x4 acc[4][4];
  #pragma unroll
  for (int m = 0; m < 4; ++m)
    #pragma unroll
    for (int n = 0; n < 4; ++n) acc[m][n] = (f32x4){0.f, 0.f, 0.f, 0.f};
  gemm_core(pw + (long)row0 * 1056, opad + ((long)b * 512 + col0) * 1056,
            1056, 1056, 33, 1 << 30, 1 << 30, As0, Bs0, As1, Bs1, acc);
  const int lane = threadIdx.x & 63, wave = threadIdx.x >> 6;
  const int wr = wave >> 1, wc = wave & 1, fr = lane & 15, fg = lane >> 4;
  #pragma unroll
  for (int m = 0; m < 4; ++m) {
    #pragma unroll
    for (int rr = 0; rr < 4; ++rr) {
      int mi = row0 + wr * 64 + m * 16 + fg * 4 + rr;
      float pb = proj_b[mi];
      #pragma unroll
      for (int n = 0; n < 4; ++n) {
        int c = col0 + wc * 64 + n * 16 + fr;
        long idx = ((long)b * 1024 + mi) * 512 + c;
        xoT[idx] = (f16)(acc[m][n][rr] + pb + (float)vcT[idx]);
      }
    }
  }
}

// ---------------------------------------------------------------------------
// out GEMM (double-slice core).  grid dim3(4,8,16); K=512 -> 16 slices
// ---------------------------------------------------------------------------
__global__ __launch_bounds__(256) void out_gemm(
    const f16* __restrict__ xoT, const f16* __restrict__ ow,
    const float* __restrict__ out_b, float* __restrict__ out)
{
  __shared__ f16 As0[128 * 40];
  __shared__ f16 Bs0[128 * 40];
  __shared__ f16 As1[128 * 40];
  __shared__ f16 Bs1[128 * 40];
  const int id = blockIdx.x + blockIdx.y * 4 + blockIdx.z * 32;  // [0,512)
  const int lin = (id & 7) * 64 + (id >> 3);                     // bijective
  const int b = lin >> 5;
  const int rc = lin & 31;
  const int row0 = (rc >> 2) * 128;
  const int col0 = (rc & 3) * 128;
  f32x4 acc[4][4];
  #pragma unroll
  for (int m = 0; m < 4; ++m)
    #pragma unroll
    for (int n = 0; n < 4; ++n) acc[m][n] = (f32x4){0.f, 0.f, 0.f, 0.f};
  gemm_core(xoT + ((long)b * 1024 + row0) * 512, ow + (long)col0 * 512,
            512, 512, 16, 1 << 30, 1 << 30, As0, Bs0, As1, Bs1, acc);
  const int lane = threadIdx.x & 63, wave = threadIdx.x >> 6;
  const int wr = wave >> 1, wc = wave & 1, fr = lane & 15, fg = lane >> 4;
  float ob[4];
  #pragma unroll
  for (int n = 0; n < 4; ++n) ob[n] = out_b[col0 + wc * 64 + n * 16 + fr];
  #pragma unroll
  for (int m = 0; m < 4; ++m) {
    #pragma unroll
    for (int rr = 0; rr < 4; ++rr) {
      int mi = row0 + wr * 64 + m * 16 + fg * 4 + rr;
      #pragma unroll
      for (int n = 0; n < 4; ++n) {
        int co = col0 + wc * 64 + n * 16 + fr;
        out[((long)b * 1024 + mi) * 512 + co] = acc[m][n][rr] + ob[n];
      }
    }
  }
}

// ---------------------------------------------------------------------------
extern "C" void kernel_launch(void* const* d_in, const int* in_sizes, int n_in,
                              void* d_out, int out_size, void* d_ws, size_t ws_size,
                              hipStream_t stream) {
  const float* x      = (const float*)d_in[0];
  const float* qkv_w  = (const float*)d_in[1];
  const float* bn_g   = (const float*)d_in[2];
  const float* bn_b   = (const float*)d_in[3];
  const float* bn_m   = (const float*)d_in[4];
  const float* bn_v   = (const float*)d_in[5];
  const float* conv_w = (const float*)d_in[6];
  const float* conv_b = (const float*)d_in[7];
  const float* proj_w = (const float*)d_in[8];
  const float* proj_b = (const float*)d_in[9];
  const float* out_w  = (const float*)d_in[10];
  const float* out_b  = (const float*)d_in[11];
  float* out = (float*)d_out;

  char* ws = (char*)d_ws;
  f16*   wq_h  = (f16*)(ws + OFF_WQ);
  f16*   pw_h  = (f16*)(ws + OFF_PW);
  f16*   ow_h  = (f16*)(ws + OFF_OW);
  float* bn_a  = (float*)(ws + OFF_BNA);
  float* bn_sh = (float*)(ws + OFF_BNB);
  f16*   qb    = (f16*)(ws + OFF_QB);
  f16*   kb    = (f16*)(ws + OFF_KB);
  f16*   vt    = (f16*)(ws + OFF_VT);
  f16*   opad  = (f16*)(ws + OFF_OPAD);
  f16*   vcT   = (f16*)(ws + OFF_VCT);
  f16*   xoT   = (f16*)(ws + OFF_XOT);

  prep_kernel<<<1024, 256, 0, stream>>>(qkv_w, bn_g, bn_b, bn_m, bn_v,
                                        proj_w, out_w, wq_h, pw_h, ow_h,
                                        bn_a, bn_sh, qb, kb, vt, opad);
  qkv_gemm<<<dim3(8, 131), 256, 0, stream>>>(x, wq_h, bn_a, bn_sh, qb, kb, vt);
  conv_kernel<<<dim3(32, 16), 256, 0, stream>>>(vt, conv_w, conv_b, vcT);
  attn_kernel<<<dim3(9, 128), 256, 0, stream>>>(qb, kb, vt, opad);
  proj_gemm<<<dim3(4, 8, 16), 256, 0, stream>>>(pw_h, opad, proj_b, vcT, xoT);
  out_gemm<<<dim3(4, 8, 16), 256, 0, stream>>>(xoT, ow_h, out_b, out);
}

// Round 15
// 171.933 us; speedup vs baseline: 1.0757x; 1.0757x over previous
//
#include <hip/hip_runtime.h>
#include <hip/hip_fp16.h>

typedef _Float16 f16;
typedef _Float16 f16x8 __attribute__((ext_vector_type(8)));
typedef _Float16 f16x4 __attribute__((ext_vector_type(4)));
typedef float    f32x4 __attribute__((ext_vector_type(4)));
typedef float    f32x16 __attribute__((ext_vector_type(16)));

#define DEV __device__ __forceinline__

DEV int imin(int a, int b) { return a < b ? a : b; }

#if defined(__has_builtin)
#  if __has_builtin(__builtin_amdgcn_exp2f)
#    define EXP2(x) __builtin_amdgcn_exp2f(x)
#  else
#    define EXP2(x) __expf((x) * 0.6931471805599453f)
#  endif
#else
#  define EXP2(x) __expf((x) * 0.6931471805599453f)
#endif

// q pre-scale: (1/sqrt(32)) * log2(e) so softmax is p = 2^s
#define QSCALE (0.17677669529663687f * 1.4426950408889634f)

// ---------------------------------------------------------------------------
// Problem constants: B=16, N=1044, DIM=512, H=8, KD=32, D=64
// q padded to 1152 rows, k/v to 1088, o cols to 1056
// ---------------------------------------------------------------------------

// workspace offsets (bytes) — round-3/6 proven layout (XH slot unused)
constexpr size_t OFF_WQ   = 17104896;     // qkv_w fp16 (1024,512)        1,048,576
constexpr size_t OFF_PW   = 18153472;     // proj_w fp16 (1024,1056)      2,162,688
constexpr size_t OFF_OW   = 20316160;     // out_w fp16 (512,512)           524,288
constexpr size_t OFF_BNA  = 20840448;     // bn scale fp32 (1024)
constexpr size_t OFF_BNB  = 20844544;     // bn shift fp32 (1024)
constexpr size_t OFF_QB   = 20848640;     // q fp16 (128,1152,32)         9,437,184
constexpr size_t OFF_KB   = 30285824;     // k fp16 (128,1088,32)         8,912,896
constexpr size_t OFF_VT   = 39198720;     // v^T fp16 (128,64,1088)      17,825,792
constexpr size_t OFF_OPAD = 57024512;     // o fp16 (16,512,1056)        17,301,504
constexpr size_t OFF_VCT  = 74326016;     // vcT fp16 (16,1024,512)      16,777,216
constexpr size_t OFF_XOT  = 91103232;     // xoT fp16 (16,1024,512)      16,777,216

DEV f32x16 zero16() {
  f32x16 z;
  #pragma unroll
  for (int i = 0; i < 16; ++i) z[i] = 0.f;
  return z;
}

DEV unsigned pk2(float a, float b) {
  auto h = __builtin_amdgcn_cvt_pkrtz(a, b);
  union { decltype(h) x; unsigned u; } t;
  t.x = h;
  return t.u;
}

DEV void plswap(unsigned &a, unsigned &b) {
  asm("v_permlane32_swap_b32 %0, %1" : "+v"(a), "+v"(b));
}

union W4 { unsigned w[4]; f16x8 v; };

DEV void pack_block(const float p[16], f16x8 &a0, f16x8 &a1) {
  unsigned w0 = pk2(p[0], p[1]),   w1 = pk2(p[2], p[3]);
  unsigned w2 = pk2(p[4], p[5]),   w3 = pk2(p[6], p[7]);
  unsigned w4 = pk2(p[8], p[9]),   w5 = pk2(p[10], p[11]);
  unsigned w6 = pk2(p[12], p[13]), w7 = pk2(p[14], p[15]);
  plswap(w0, w2); plswap(w1, w3);
  plswap(w4, w6); plswap(w5, w7);
  W4 u; u.w[0] = w0; u.w[1] = w1; u.w[2] = w2; u.w[3] = w3; a0 = u.v;
  W4 v; v.w[0] = w4; v.w[1] = w5; v.w[2] = w6; v.w[3] = w7; a1 = v.v;
}

// ---------------------------------------------------------------------------
// prep: weight fp16 conversions, BN fold, zero pads (x round-trip removed)
// ---------------------------------------------------------------------------
__global__ __launch_bounds__(256) void prep_kernel(
    const float* __restrict__ qkv_w,
    const float* __restrict__ bn_g, const float* __restrict__ bn_b,
    const float* __restrict__ bn_m, const float* __restrict__ bn_v,
    const float* __restrict__ proj_w, const float* __restrict__ out_w,
    f16* __restrict__ wq_h, f16* __restrict__ pw_h, f16* __restrict__ ow_h,
    float* __restrict__ bn_a, float* __restrict__ bn_sh,
    f16* __restrict__ qb, f16* __restrict__ kb, f16* __restrict__ vt,
    f16* __restrict__ opad)
{
  long tid = (long)blockIdx.x * blockDim.x + threadIdx.x;
  long gsz = (long)gridDim.x * blockDim.x;

  for (long i = tid; i < 524288; i += gsz) wq_h[i] = (f16)qkv_w[i];
  for (long i = tid; i < 1081344; i += gsz) {
    long m = i / 1056, nn = i - m * 1056;
    pw_h[i] = (nn < 1044) ? (f16)proj_w[m * 1044 + nn] : (f16)0.f;
  }
  for (long i = tid; i < 262144; i += gsz) ow_h[i] = (f16)out_w[i];
  for (long i = tid; i < 1024; i += gsz) {
    float a = bn_g[i] * rsqrtf(bn_v[i] + 1e-5f);
    bn_a[i] = a;
    bn_sh[i] = bn_b[i] - bn_m[i] * a;
  }
  for (long i = tid; i < 13824; i += gsz) {
    int bh = (int)(i / 108);
    int nn = 1044 + (int)(i - (long)bh * 108);
    f16* q = qb + ((long)bh * 1152 + nn) * 32;
    for (int j = 0; j < 32; ++j) q[j] = (f16)0.f;
  }
  for (long i = tid; i < 5632; i += gsz) {
    int bh = (int)(i / 44);
    int nn = 1044 + (int)(i - (long)bh * 44);
    f16* k = kb + ((long)bh * 1088 + nn) * 32;
    for (int j = 0; j < 32; ++j) k[j] = (f16)0.f;
  }
  for (long i = tid; i < 8192; i += gsz) {
    f16* v = vt + i * 1088 + 1044;
    for (int j = 0; j < 44; ++j) v[j] = (f16)0.f;
  }
  for (long i = tid; i < 8192; i += gsz) {
    f16* o = opad + i * 1056 + 1044;
    for (int j = 0; j < 12; ++j) o[j] = (f16)0.f;
  }
}

// ---------------------------------------------------------------------------
// shared 128x128xK NT-GEMM core (r7/r9 proven: BK=32, LDS stride 40, single
// buffer, 2 barriers, T14 prefetch after barrier2; clamps on both sides)
// ---------------------------------------------------------------------------
DEV void gemm_core(const f16* __restrict__ A, const f16* __restrict__ B,
                   int lda, int ldb, int kIters, int rowClampA, int rowClampB,
                   f16* As, f16* Bs, f32x4 acc[4][4])
{
  const int t = threadIdx.x;
  const int wave = t >> 6, lane = t & 63;
  const int wr = wave >> 1, wc = wave & 1;
  const int r0 = t >> 2, seg = t & 3;
  const int fr = lane & 15, fg = lane >> 4;
  const int ra0 = imin(r0, rowClampA);
  const int ra1 = imin(r0 + 64, rowClampA);
  const int rb0 = imin(r0, rowClampB);
  const int rb1 = imin(r0 + 64, rowClampB);

  const f16* pa0 = A + (long)ra0 * lda + seg * 8;
  const f16* pa1 = A + (long)ra1 * lda + seg * 8;
  const f16* pb0 = B + (long)rb0 * ldb + seg * 8;
  const f16* pb1 = B + (long)rb1 * ldb + seg * 8;

  f16x8 a0, a1, b0, b1;
  a0 = *(const f16x8*)(pa0);
  a1 = *(const f16x8*)(pa1);
  b0 = *(const f16x8*)(pb0);
  b1 = *(const f16x8*)(pb1);

  #pragma unroll 1
  for (int kt = 0; kt < kIters; ++kt) {
    __syncthreads();
    *(f16x8*)(As + r0 * 40 + seg * 8) = a0;
    *(f16x8*)(As + (r0 + 64) * 40 + seg * 8) = a1;
    *(f16x8*)(Bs + r0 * 40 + seg * 8) = b0;
    *(f16x8*)(Bs + (r0 + 64) * 40 + seg * 8) = b1;
    __syncthreads();
    if (kt + 1 < kIters) {
      const int kb = (kt + 1) * 32;
      a0 = *(const f16x8*)(pa0 + kb);
      a1 = *(const f16x8*)(pa1 + kb);
      b0 = *(const f16x8*)(pb0 + kb);
      b1 = *(const f16x8*)(pb1 + kb);
    }
    f16x8 af[4], bf[4];
    #pragma unroll
    for (int m = 0; m < 4; ++m)
      af[m] = *(const f16x8*)(As + (wr * 64 + m * 16 + fr) * 40 + fg * 8);
    #pragma unroll
    for (int n = 0; n < 4; ++n)
      bf[n] = *(const f16x8*)(Bs + (wc * 64 + n * 16 + fr) * 40 + fg * 8);
    #pragma unroll
    for (int m = 0; m < 4; ++m)
      #pragma unroll
      for (int n = 0; n < 4; ++n)
        acc[m][n] = __builtin_amdgcn_mfma_f32_16x16x32_f16(af[m], bf[n], acc[m][n], 0, 0, 0);
  }
}

// ---------------------------------------------------------------------------
// variant: B side is FP32 (x read directly from HBM), converted in-reg
// during staging; identical LDS layout/pipeline.
// ---------------------------------------------------------------------------
DEV void gemm_core_xf32(const f16* __restrict__ A, const float* __restrict__ B,
                        int lda, int ldb, int kIters, int rowClampB,
                        f16* As, f16* Bs, f32x4 acc[4][4])
{
  const int t = threadIdx.x;
  const int wave = t >> 6, lane = t & 63;
  const int wr = wave >> 1, wc = wave & 1;
  const int r0 = t >> 2, seg = t & 3;
  const int fr = lane & 15, fg = lane >> 4;
  const int rb0 = imin(r0, rowClampB);
  const int rb1 = imin(r0 + 64, rowClampB);

  const f16*   pa0 = A + (long)r0 * lda + seg * 8;
  const f16*   pa1 = A + (long)(r0 + 64) * lda + seg * 8;
  const float* pb0 = B + (long)rb0 * ldb + seg * 8;
  const float* pb1 = B + (long)rb1 * ldb + seg * 8;

  f16x8 a0, a1;
  float4 b0l, b0h, b1l, b1h;
  auto cvt8 = [](float4 lo, float4 hi) -> f16x8 {
    f16x8 r;
    r[0] = (f16)lo.x; r[1] = (f16)lo.y; r[2] = (f16)lo.z; r[3] = (f16)lo.w;
    r[4] = (f16)hi.x; r[5] = (f16)hi.y; r[6] = (f16)hi.z; r[7] = (f16)hi.w;
    return r;
  };
  a0 = *(const f16x8*)(pa0);
  a1 = *(const f16x8*)(pa1);
  b0l = ((const float4*)pb0)[0]; b0h = ((const float4*)pb0)[1];
  b1l = ((const float4*)pb1)[0]; b1h = ((const float4*)pb1)[1];

  #pragma unroll 1
  for (int kt = 0; kt < kIters; ++kt) {
    __syncthreads();
    *(f16x8*)(As + r0 * 40 + seg * 8) = a0;
    *(f16x8*)(As + (r0 + 64) * 40 + seg * 8) = a1;
    *(f16x8*)(Bs + r0 * 40 + seg * 8) = cvt8(b0l, b0h);
    *(f16x8*)(Bs + (r0 + 64) * 40 + seg * 8) = cvt8(b1l, b1h);
    __syncthreads();
    if (kt + 1 < kIters) {
      const int kb = (kt + 1) * 32;
      a0 = *(const f16x8*)(pa0 + kb);
      a1 = *(const f16x8*)(pa1 + kb);
      b0l = ((const float4*)(pb0 + kb))[0]; b0h = ((const float4*)(pb0 + kb))[1];
      b1l = ((const float4*)(pb1 + kb))[0]; b1h = ((const float4*)(pb1 + kb))[1];
    }
    f16x8 af[4], bf[4];
    #pragma unroll
    for (int m = 0; m < 4; ++m)
      af[m] = *(const f16x8*)(As + (wr * 64 + m * 16 + fr) * 40 + fg * 8);
    #pragma unroll
    for (int n = 0; n < 4; ++n)
      bf[n] = *(const f16x8*)(Bs + (wc * 64 + n * 16 + fr) * 40 + fg * 8);
    #pragma unroll
    for (int m = 0; m < 4; ++m)
      #pragma unroll
      for (int n = 0; n < 4; ++n)
        acc[m][n] = __builtin_amdgcn_mfma_f32_16x16x32_f16(af[m], bf[n], acc[m][n], 0, 0, 0);
  }
}

// ---------------------------------------------------------------------------
// QKV GEMM, transposed: A = wq_h (f16), B = x (FP32 direct).  grid (8,131)
// ---------------------------------------------------------------------------
__global__ __launch_bounds__(256) void qkv_gemm(
    const float* __restrict__ x, const f16* __restrict__ wq,
    const float* __restrict__ bn_a, const float* __restrict__ bn_sh,
    f16* __restrict__ qb, f16* __restrict__ kb, f16* __restrict__ vt)
{
  __shared__ f16 As[128 * 40];
  __shared__ f16 Bs[128 * 40];
  const int id = blockIdx.x + blockIdx.y * 8;          // [0,1048)
  const int lin = (id & 7) * 131 + (id >> 3);          // bijective [0,1048)
  const int row0 = (lin & 7) * 128;                    // channel block
  const int col0 = (lin >> 3) * 128;                   // token block (banded)
  f32x4 acc[4][4];
  #pragma unroll
  for (int m = 0; m < 4; ++m)
    #pragma unroll
    for (int n = 0; n < 4; ++n) acc[m][n] = (f32x4){0.f, 0.f, 0.f, 0.f};
  gemm_core_xf32(wq + (long)row0 * 512, x + (long)col0 * 512, 512, 512, 16,
                 16703 - col0, As, Bs, acc);
  const int lane = threadIdx.x & 63, wave = threadIdx.x >> 6;
  const int wr = wave >> 1, wc = wave & 1, fr = lane & 15, fg = lane >> 4;
  #pragma unroll
  for (int m = 0; m < 4; ++m) {
    const int chBase = row0 + wr * 64 + m * 16 + fg * 4;   // channel quad
    const float4 ba4 = *(const float4*)(bn_a + chBase);
    const float4 bs4 = *(const float4*)(bn_sh + chBase);
    const int hh = chBase >> 7, r = chBase & 127;          // quad-uniform cat
    #pragma unroll
    for (int n = 0; n < 4; ++n) {
      int tok = col0 + wc * 64 + n * 16 + fr;
      if (tok < 16704) {
        int bi = tok / 1044;
        int ni = tok - bi * 1044;
        long bh = (long)(bi * 8 + hh);
        float v0 = acc[m][n][0] * ba4.x + bs4.x;
        float v1 = acc[m][n][1] * ba4.y + bs4.y;
        float v2 = acc[m][n][2] * ba4.z + bs4.z;
        float v3 = acc[m][n][3] * ba4.w + bs4.w;
        if (r < 32) {
          f16x4 pk = {(f16)(v0 * QSCALE), (f16)(v1 * QSCALE),
                      (f16)(v2 * QSCALE), (f16)(v3 * QSCALE)};
          *(f16x4*)(qb + (bh * 1152 + ni) * 32 + r) = pk;
        } else if (r < 64) {
          f16x4 pk = {(f16)v0, (f16)v1, (f16)v2, (f16)v3};
          *(f16x4*)(kb + (bh * 1088 + ni) * 32 + (r - 32)) = pk;
        } else {
          f16* vp = vt + (bh * 64 + (r - 64)) * 1088 + ni;
          vp[0]        = (f16)v0;
          vp[1088]     = (f16)v1;
          vp[2 * 1088] = (f16)v2;
          vp[3 * 1088] = (f16)v3;
        }
      }
    }
  }
}

// ---------------------------------------------------------------------------
// depthwise conv branch (verbatim)
// ---------------------------------------------------------------------------
__global__ __launch_bounds__(256) void conv_kernel(
    const f16* __restrict__ vt, const float* __restrict__ conv_w,
    const float* __restrict__ conv_b, f16* __restrict__ vcT)
{
  __shared__ f16 img[16][34][36];
  const int b = blockIdx.y, g = blockIdx.x;
  const int c0 = g * 16, h = c0 >> 6, ci0 = c0 & 63;
  const int t = threadIdx.x;
  for (int i = t; i < 16 * 34 * 36; i += 256) ((f16*)img)[i] = (f16)0.f;
  __syncthreads();
  const int d = t >> 2, seg = t & 3;
  const f16* src = vt + ((long)(b * 8 + h) * 64 + d) * 1088 + ci0 * 16 + seg * 64;
  const int dhib = d >> 5;
  const int s2 = d & 31;
  #pragma unroll
  for (int j = 0; j < 8; ++j) {
    f16x8 vv = *(const f16x8*)(src + j * 8);
    #pragma unroll
    for (int e = 0; e < 8; ++e) {
      int local = seg * 64 + j * 8 + e;
      int cl = local >> 4, rr = local & 15;
      float xv = (float)vv[e];
      float hs = xv * fminf(fmaxf(xv + 3.f, 0.f), 6.f) * (1.f / 6.f);
      img[cl][1 + rr * 2 + dhib][1 + s2] = (f16)hs;
    }
  }
  __syncthreads();
  const int cl = t & 15, pg = t >> 4;
  const int c = c0 + cl;
  float w[9];
  #pragma unroll
  for (int i = 0; i < 9; ++i) w[i] = conv_w[c * 9 + i];
  const float bias = conv_b[c];
  for (int i = 0; i < 64; ++i) {
    int p = pg + i * 16;
    int s1 = p >> 5, ss2 = p & 31;
    float a = bias;
    #pragma unroll
    for (int di = 0; di < 3; ++di)
      #pragma unroll
      for (int dj = 0; dj < 3; ++dj)
        a += w[di * 3 + dj] * (float)img[cl][s1 + di][ss2 + dj];
    vcT[((long)b * 1024 + p) * 512 + c] = (f16)a;
  }
}

// ---------------------------------------------------------------------------
// fused attention — r9-proven (66-68 us) verbatim.  k-tile=32, 4 waves,
// shared double-buffered LDS, setprio on PV.  grid (9,128), XCD-grouped.
// ---------------------------------------------------------------------------
__global__ __launch_bounds__(256, 4) void attn_kernel(
    const f16* __restrict__ qb, const f16* __restrict__ kb,
    const f16* __restrict__ vt, f16* __restrict__ opad)
{
  __shared__ f16 kls[2][4 * 32 * 8];   // 2 KB/buf
  __shared__ f16 vls[2][4 * 64 * 8];   // 4 KB/buf
  __shared__ float l_sh[4][32];

  const int id = blockIdx.x + blockIdx.y * 9;
  const int xcd = id & 7, sl = id >> 3;
  const int bh = xcd * 16 + sl / 9, qblk = sl % 9;
  const int b = bh >> 3, h = bh & 7;
  const int t = threadIdx.x;
  const int wave = t >> 6, lane = t & 63;
  const int lq = lane & 31, hi = lane >> 5;
  const int q0 = qblk * 128 + wave * 32;

  const f16* qb_ = qb + (long)bh * 1152 * 32;
  const f16* kb_ = kb + (long)bh * 1088 * 32;
  const f16* vt_ = vt + (long)bh * 64 * 1088;

  const f16x8 qf0 = *(const f16x8*)(qb_ + (long)(q0 + lq) * 32 + hi * 8);
  const f16x8 qf1 = *(const f16x8*)(qb_ + (long)(q0 + lq) * 32 + 16 + hi * 8);

  const int sk_k = t >> 3, sk_s8 = t & 7;
  const int sk_seg = sk_s8 >> 1, sk_half = sk_s8 & 1;
  const int sv_d = t >> 2, sv_p = t & 3;
  const int wkoff = (sk_seg * 32 + ((sk_k + sk_seg) & 31)) * 16 + sk_half * 8;
  const int wvoff = (sv_p * 64 + ((sv_d + sv_p) & 63)) * 16;
  int koff[2], voff[2][2];
  #pragma unroll
  for (int ss = 0; ss < 2; ++ss) {
    int ss2 = 2 * ss + hi;
    koff[ss] = (ss2 * 32 + ((lq + ss2) & 31)) * 16;
  }
  #pragma unroll
  for (int nd = 0; nd < 2; ++nd)
    #pragma unroll
    for (int ks = 0; ks < 2; ++ks) {
      int kk4 = 2 * ks + hi;
      voff[nd][ks] = (kk4 * 64 + ((nd * 32 + lq + kk4) & 63)) * 16;
    }

  f16x4 stk;
  f16x8 stv;
  auto load_tile = [&](int kt) {
    stk = *(const f16x4*)(kb_ + (long)(kt * 32 + sk_k) * 32 + sk_s8 * 4);
    stv = *(const f16x8*)(vt_ + (long)sv_d * 1088 + kt * 32 + sv_p * 8);
  };
  auto write_tile = [&](int buf) {
    *(f16x4*)((char*)kls[buf] + wkoff) = stk;
    *(f16x8*)((char*)vls[buf] + wvoff) = stv;
  };

  f32x16 o0 = zero16(), o1 = zero16();
  float lsum = 0.f;

  load_tile(0);
  write_tile(0);
  __syncthreads();

  int cur = 0;
  #pragma unroll 1
  for (int kt = 0; kt < 33; ++kt) {
    if (kt < 32) load_tile(kt + 1);
    const char* kcur = (const char*)kls[cur];
    const char* vcur = (const char*)vls[cur];
    f16x8 kf0 = *(const f16x8*)(kcur + koff[0]);
    f16x8 kf1 = *(const f16x8*)(kcur + koff[1]);
    f32x16 s = zero16();
    s = __builtin_amdgcn_mfma_f32_32x32x16_f16(kf0, qf0, s, 0, 0, 0);
    s = __builtin_amdgcn_mfma_f32_32x32x16_f16(kf1, qf1, s, 0, 0, 0);
    float p[16];
    #pragma unroll
    for (int r = 0; r < 16; ++r) p[r] = EXP2(s[r]);
    if (kt == 32) {
      #pragma unroll
      for (int r = 0; r < 16; ++r) {
        int cr = (r & 3) + 8 * (r >> 2) + 4 * hi;
        p[r] = (cr < 20) ? p[r] : 0.f;
      }
    }
    float t8[8];
    #pragma unroll
    for (int r = 0; r < 8; ++r) t8[r] = p[r] + p[r + 8];
    lsum += ((t8[0] + t8[1]) + (t8[2] + t8[3])) + ((t8[4] + t8[5]) + (t8[6] + t8[7]));
    f16x8 pa0, pa1;
    pack_block(p, pa0, pa1);
    __builtin_amdgcn_s_setprio(1);
    {
      f16x8 vf00 = *(const f16x8*)(vcur + voff[0][0]);
      f16x8 vf10 = *(const f16x8*)(vcur + voff[1][0]);
      o0 = __builtin_amdgcn_mfma_f32_32x32x16_f16(pa0, vf00, o0, 0, 0, 0);
      o1 = __builtin_amdgcn_mfma_f32_32x32x16_f16(pa0, vf10, o1, 0, 0, 0);
      f16x8 vf01 = *(const f16x8*)(vcur + voff[0][1]);
      f16x8 vf11 = *(const f16x8*)(vcur + voff[1][1]);
      o0 = __builtin_amdgcn_mfma_f32_32x32x16_f16(pa1, vf01, o0, 0, 0, 0);
      o1 = __builtin_amdgcn_mfma_f32_32x32x16_f16(pa1, vf11, o1, 0, 0, 0);
    }
    __builtin_amdgcn_s_setprio(0);
    if (kt < 32) write_tile(cur ^ 1);
    __syncthreads();
    cur ^= 1;
  }

  lsum += __shfl_xor(lsum, 32);
  l_sh[wave][lq] = lsum;
  __syncthreads();
  float invl[16];
  #pragma unroll
  for (int r = 0; r < 16; ++r) {
    int cr = (r & 3) + 8 * (r >> 2) + 4 * hi;
    invl[r] = __builtin_amdgcn_rcpf(l_sh[wave][cr]);
  }
  #pragma unroll
  for (int nd = 0; nd < 2; ++nd) {
    #pragma unroll
    for (int r = 0; r < 16; ++r) {
      int cr = (r & 3) + 8 * (r >> 2) + 4 * hi;
      int q = q0 + cr;
      if (q < 1044) {
        float val = (nd ? o1[r] : o0[r]) * invl[r];
        unsigned flat = (unsigned)q * 512u + (unsigned)h * 64u + (unsigned)(nd * 32 + lq);
        unsigned c = flat / 1044u;
        unsigned np = flat - c * 1044u;
        opad[((long)b * 512 + c) * 1056 + np] = (f16)val;
      }
    }
  }
}

// ---------------------------------------------------------------------------
// proj GEMM (r9 verbatim).  grid dim3(4,8,16)
// ---------------------------------------------------------------------------
__global__ __launch_bounds__(256) void proj_gemm(
    const f16* __restrict__ pw, const f16* __restrict__ opad,
    const float* __restrict__ proj_b, const f16* __restrict__ vcT,
    f16* __restrict__ xoT)
{
  __shared__ f16 As[128 * 40];
  __shared__ f16 Bs[128 * 40];
  const int id = blockIdx.x + blockIdx.y * 4 + blockIdx.z * 32;  // [0,512)
  const int lin = (id & 7) * 64 + (id >> 3);                     // bijective
  const int b = lin >> 5;
  const int rc = lin & 31;
  const int row0 = (rc >> 2) * 128;  // m (image pixel)
  const int col0 = (rc & 3) * 128;   // c (channel)
  f32x4 acc[4][4];
  #pragma unroll
  for (int m = 0; m < 4; ++m)
    #pragma unroll
    for (int n = 0; n < 4; ++n) acc[m][n] = (f32x4){0.f, 0.f, 0.f, 0.f};
  gemm_core(pw + (long)row0 * 1056, opad + ((long)b * 512 + col0) * 1056,
            1056, 1056, 33, 1 << 30, 1 << 30, As, Bs, acc);
  const int lane = threadIdx.x & 63, wave = threadIdx.x >> 6;
  const int wr = wave >> 1, wc = wave & 1, fr = lane & 15, fg = lane >> 4;
  #pragma unroll
  for (int m = 0; m < 4; ++m) {
    #pragma unroll
    for (int rr = 0; rr < 4; ++rr) {
      int mi = row0 + wr * 64 + m * 16 + fg * 4 + rr;
      float pb = proj_b[mi];
      #pragma unroll
      for (int n = 0; n < 4; ++n) {
        int c = col0 + wc * 64 + n * 16 + fr;
        long idx = ((long)b * 1024 + mi) * 512 + c;
        xoT[idx] = (f16)(acc[m][n][rr] + pb + (float)vcT[idx]);
      }
    }
  }
}

// ---------------------------------------------------------------------------
// out GEMM (r9 verbatim).  grid dim3(4,8,16)
// ---------------------------------------------------------------------------
__global__ __launch_bounds__(256) void out_gemm(
    const f16* __restrict__ xoT, const f16* __restrict__ ow,
    const float* __restrict__ out_b, float* __restrict__ out)
{
  __shared__ f16 As[128 * 40];
  __shared__ f16 Bs[128 * 40];
  const int id = blockIdx.x + blockIdx.y * 4 + blockIdx.z * 32;  // [0,512)
  const int lin = (id & 7) * 64 + (id >> 3);                     // bijective
  const int b = lin >> 5;
  const int rc = lin & 31;
  const int row0 = (rc >> 2) * 128;
  const int col0 = (rc & 3) * 128;
  f32x4 acc[4][4];
  #pragma unroll
  for (int m = 0; m < 4; ++m)
    #pragma unroll
    for (int n = 0; n < 4; ++n) acc[m][n] = (f32x4){0.f, 0.f, 0.f, 0.f};
  gemm_core(xoT + ((long)b * 1024 + row0) * 512, ow + (long)col0 * 512,
            512, 512, 16, 1 << 30, 1 << 30, As, Bs, acc);
  const int lane = threadIdx.x & 63, wave = threadIdx.x >> 6;
  const int wr = wave >> 1, wc = wave & 1, fr = lane & 15, fg = lane >> 4;
  float ob[4];
  #pragma unroll
  for (int n = 0; n < 4; ++n) ob[n] = out_b[col0 + wc * 64 + n * 16 + fr];
  #pragma unroll
  for (int m = 0; m < 4; ++m) {
    #pragma unroll
    for (int rr = 0; rr < 4; ++rr) {
      int mi = row0 + wr * 64 + m * 16 + fg * 4 + rr;
      #pragma unroll
      for (int n = 0; n < 4; ++n) {
        int co = col0 + wc * 64 + n * 16 + fr;
        out[((long)b * 1024 + mi) * 512 + co] = acc[m][n][rr] + ob[n];
      }
    }
  }
}

// ---------------------------------------------------------------------------
extern "C" void kernel_launch(void* const* d_in, const int* in_sizes, int n_in,
                              void* d_out, int out_size, void* d_ws, size_t ws_size,
                              hipStream_t stream) {
  const float* x      = (const float*)d_in[0];
  const float* qkv_w  = (const float*)d_in[1];
  const float* bn_g   = (const float*)d_in[2];
  const float* bn_b   = (const float*)d_in[3];
  const float* bn_m   = (const float*)d_in[4];
  const float* bn_v   = (const float*)d_in[5];
  const float* conv_w = (const float*)d_in[6];
  const float* conv_b = (const float*)d_in[7];
  const float* proj_w = (const float*)d_in[8];
  const float* proj_b = (const float*)d_in[9];
  const float* out_w  = (const float*)d_in[10];
  const float* out_b  = (const float*)d_in[11];
  float* out = (float*)d_out;

  char* ws = (char*)d_ws;
  f16*   wq_h  = (f16*)(ws + OFF_WQ);
  f16*   pw_h  = (f16*)(ws + OFF_PW);
  f16*   ow_h  = (f16*)(ws + OFF_OW);
  float* bn_a  = (float*)(ws + OFF_BNA);
  float* bn_sh = (float*)(ws + OFF_BNB);
  f16*   qb    = (f16*)(ws + OFF_QB);
  f16*   kb    = (f16*)(ws + OFF_KB);
  f16*   vt    = (f16*)(ws + OFF_VT);
  f16*   opad  = (f16*)(ws + OFF_OPAD);
  f16*   vcT   = (f16*)(ws + OFF_VCT);
  f16*   xoT   = (f16*)(ws + OFF_XOT);

  prep_kernel<<<1024, 256, 0, stream>>>(qkv_w, bn_g, bn_b, bn_m, bn_v,
                                        proj_w, out_w, wq_h, pw_h, ow_h,
                                        bn_a, bn_sh, qb, kb, vt, opad);
  qkv_gemm<<<dim3(8, 131), 256, 0, stream>>>(x, wq_h, bn_a, bn_sh, qb, kb, vt);
  conv_kernel<<<dim3(32, 16), 256, 0, stream>>>(vt, conv_w, conv_b, vcT);
  attn_kernel<<<dim3(9, 128), 256, 0, stream>>>(qb, kb, vt, opad);
  proj_gemm<<<dim3(4, 8, 16), 256, 0, stream>>>(pw_h, opad, proj_b, vcT, xoT);
  out_gemm<<<dim3(4, 8, 16), 256, 0, stream>>>(xoT, ow_h, out_b, out);
}